// Round 2
// baseline (792.932 us; speedup 1.0000x reference)
//
#include <hip/hip_runtime.h>
#include <hip/hip_bf16.h>

// Problem constants
#define Hq   16
#define HKV  4
#define Dh   128
#define ROT  64
#define BLKQ 64
#define NBLK 64      // T/BLK
#define Tlen 4096
#define Bsz  2
#define HID  2048
#define QKVC 3072    // 2048 q + 512 k + 512 v
#define SCALE_C 0.08838834764831845f

typedef __attribute__((ext_vector_type(8))) short bf16x8;
typedef __attribute__((ext_vector_type(4))) float f32x4;

#define MFMA16(a, b, c) __builtin_amdgcn_mfma_f32_16x16x32_bf16((a), (b), (c), 0, 0, 0)

__device__ __forceinline__ void async_copy16(__hip_bfloat16* lds, const __hip_bfloat16* g) {
    __builtin_amdgcn_global_load_lds(
        (const __attribute__((address_space(1))) void*)g,
        (__attribute__((address_space(3))) void*)lds,
        16, 0, 0);
}

// Runtime dtype probe: cos[t=0] row is exactly 1.0. First u32 of the buffer:
// f32 -> 0x3F800000 ; bf16 pair (1.0,1.0) -> 0x3F803F80.
__global__ void detect_dtype(const void* __restrict__ cosraw, int* __restrict__ flag) {
    if (threadIdx.x == 0 && blockIdx.x == 0) {
        unsigned x = *(const unsigned*)cosraw;
        *flag = (x == 0x3F800000u) ? 1 : 0;   // 1 = inputs/outputs are f32
    }
}

__device__ __forceinline__ bf16x8 cvt8(const float* src) {
    union { bf16x8 v; __hip_bfloat16 e[8]; } u;
#pragma unroll
    for (int j = 0; j < 8; ++j) u.e[j] = __float2bfloat16(src[j]);
    return u.v;
}

// C[M,N] = A[M,K] * B[N,K]^T. Compute in bf16 MFMA. DA/DB/DC: that operand's
// dtype depends on the runtime flag (f32 vs bf16); otherwise it is bf16 always.
// m97-style: 128x128 tile, BK=64, global_load_lds width 16 (bf16 path) or
// manual f32->bf16 cvt staging (f32 path), XOR chunk swizzle for ds_read_b128.
template <bool DA, bool DB, bool DC>
__global__ __launch_bounds__(256) void gemm_bt(
    const void* __restrict__ A,
    const void* __restrict__ B0,
    const void* __restrict__ B1,
    const void* __restrict__ B2,
    int n1, int n2,
    void* __restrict__ C,
    int M, int N, int K,
    const int* __restrict__ flagp)
{
    __shared__ __align__(16) __hip_bfloat16 As[128 * 64];
    __shared__ __align__(16) __hip_bfloat16 Bs[128 * 64];

    const int f32m = (DA || DB || DC) ? *flagp : 0;

    const int m0 = blockIdx.y * 128;
    const int n0 = blockIdx.x * 128;
    const void* Bp;
    int nb;
    if (n0 < n1)      { Bp = B0; nb = n0; }
    else if (n0 < n2) { Bp = B1; nb = n0 - n1; }
    else              { Bp = B2; nb = n0 - n2; }

    const int tid  = threadIdx.x;
    const int lane = tid & 63;
    const int w    = tid >> 6;          // wave 0..3
    const int wm   = (w >> 1) * 64;
    const int wn   = (w & 1) * 64;
    const int lr   = lane >> 3;         // row within 8-row staging group
    const int lc   = lane & 7;          // chunk 0..7
    const int m16  = lane & 15;
    const int q8   = lane >> 4;

    f32x4 acc[4][4] = {};

    for (int k0 = 0; k0 < K; k0 += 64) {
        __syncthreads();   // previous iteration's LDS reads done
        // Swizzle: LDS slot (row, cs) holds global chunk cg = cs ^ (row&7).
        for (int ii = 0; ii < 4; ++ii) {
            const int r8 = w * 32 + ii * 8;
            const int r  = r8 + lr;
            const int cg = lc ^ (r & 7);
            // A tile
            if (DA && f32m) {
                const float* src = (const float*)A + (size_t)(m0 + r) * K + k0 + cg * 8;
                *(bf16x8*)&As[r * 64 + lc * 8] = cvt8(src);
            } else {
                async_copy16(&As[r8 * 64],
                             (const __hip_bfloat16*)A + (size_t)(m0 + r) * K + k0 + cg * 8);
            }
            // B tile
            if (DB && f32m) {
                const float* src = (const float*)Bp + (size_t)(nb + r) * K + k0 + cg * 8;
                *(bf16x8*)&Bs[r * 64 + lc * 8] = cvt8(src);
            } else {
                async_copy16(&Bs[r8 * 64],
                             (const __hip_bfloat16*)Bp + (size_t)(nb + r) * K + k0 + cg * 8);
            }
        }
        __syncthreads();   // drains vmcnt/lgkmcnt before use

        for (int ks = 0; ks < 2; ++ks) {
            bf16x8 af[4], bfr[4];
            for (int t = 0; t < 4; ++t) {
                const int row = wm + t * 16 + m16;
                const int csA = (ks * 4 + q8) ^ (row & 7);
                af[t] = *(const bf16x8*)&As[row * 64 + csA * 8];
                const int col = wn + t * 16 + m16;
                const int csB = (ks * 4 + q8) ^ (col & 7);
                bfr[t] = *(const bf16x8*)&Bs[col * 64 + csB * 8];
            }
            for (int i = 0; i < 4; ++i)
                for (int j = 0; j < 4; ++j)
                    acc[i][j] = MFMA16(af[i], bfr[j], acc[i][j]);
        }
    }

    // epilogue: C layout col=lane&15, row=(lane>>4)*4+reg
    for (int i = 0; i < 4; ++i)
        for (int j = 0; j < 4; ++j)
            for (int r = 0; r < 4; ++r) {
                const int row = m0 + wm + i * 16 + q8 * 4 + r;
                const int col = n0 + wn + j * 16 + m16;
                if (DC && f32m)
                    ((float*)C)[(size_t)row * N + col] = acc[i][j][r];
                else
                    ((__hip_bfloat16*)C)[(size_t)row * N + col] = __float2bfloat16(acc[i][j][r]);
            }
}

// In-place RoPE on q (first 64 dims of each q head) and k (first 64 of each kv head).
// cos[d] == cos[d+32], so each thread handles the (d, d+32) pair.
__global__ void rope_kernel(__hip_bfloat16* __restrict__ qkv,
                            const void* __restrict__ cosb,
                            const void* __restrict__ sinb,
                            const int* __restrict__ flagp)
{
    const int f32m = *flagp;
    const int bt   = blockIdx.x;          // b*4096+t
    const int head = threadIdx.x >> 5;    // 0..19 (16 q heads + 4 kv heads)
    const int d    = threadIdx.x & 31;
    const int col  = (head < Hq) ? head * Dh + d : HID + (head - Hq) * Dh + d;
    __hip_bfloat16* p = qkv + (size_t)bt * QKVC + col;
    float c, s;
    if (f32m) {
        c = ((const float*)cosb)[(size_t)bt * ROT + d];
        s = ((const float*)sinb)[(size_t)bt * ROT + d];
    } else {
        c = __bfloat162float(((const __hip_bfloat16*)cosb)[(size_t)bt * ROT + d]);
        s = __bfloat162float(((const __hip_bfloat16*)sinb)[(size_t)bt * ROT + d]);
    }
    const float x1 = __bfloat162float(p[0]);
    const float x2 = __bfloat162float(p[32]);
    p[0]  = __float2bfloat16(x1 * c - x2 * s);
    p[32] = __float2bfloat16(x2 * c + x1 * s);
}

// Block-sparse flash attention. Grid (qblock=64, head=16, batch=2), 256 threads.
// Wave w owns q rows w*16..w*16+15. Per KV block: stage K and V^T in LDS,
// QK^T MFMA, in-register online softmax (shfl-xor over low 4 lane bits),
// P via per-wave LDS with a BARRIER between write and read (C->A layout), PV MFMA.
__global__ __launch_bounds__(256) void attn_kernel(
    const __hip_bfloat16* __restrict__ qkv,
    __hip_bfloat16* __restrict__ outb)
{
    const int i   = blockIdx.x;   // q block
    const int h   = blockIdx.y;
    const int b   = blockIdx.z;
    const int kvh = h >> 2;
    const int tid  = threadIdx.x;
    const int lane = tid & 63;
    const int w    = tid >> 6;
    const int m16  = lane & 15;
    const int q8   = lane >> 4;

    __shared__ __align__(16) __hip_bfloat16 Ks[64 * 136];   // K rows padded +8
    __shared__ __align__(16) __hip_bfloat16 VT[128 * 72];   // V^T rows padded +8
    __shared__ __align__(16) __hip_bfloat16 Pb[4][16 * 72]; // per-wave P scratch

    // Q fragments (A-layout): row = lane&15 (+w*16), k-chunk = (lane>>4)*8
    bf16x8 qf[4];
    {
        const __hip_bfloat16* qp =
            qkv + (size_t)(b * Tlen + i * BLKQ + w * 16 + m16) * QKVC + h * Dh + q8 * 8;
        for (int ks = 0; ks < 4; ++ks) qf[ks] = *(const bf16x8*)(qp + ks * 32);
    }

    f32x4 o[8] = {};
    float mrow[4] = {-1e30f, -1e30f, -1e30f, -1e30f};
    float lrow[4] = {0.f, 0.f, 0.f, 0.f};

    const int nsel = (i + 1 < 9) ? (i + 1) : 9;
    for (int j = 0; j < nsel; ++j) {
        const int kb = (i <= 7) ? j : ((j == 0) ? 0 : (i - 8 + j));

        __syncthreads();  // LDS reuse guard (prev iter's reads done)
        {   // cooperative K/V staging (V transposed into VT)
            const __hip_bfloat16* kbase =
                qkv + (size_t)(b * Tlen + kb * BLKQ) * QKVC + HID + kvh * Dh;
            const __hip_bfloat16* vbase = kbase + 512;
            for (int c = tid; c < 1024; c += 256) {
                const int key = c >> 4;
                const int d0  = (c & 15) * 8;
                bf16x8 k8 = *(const bf16x8*)(kbase + (size_t)key * QKVC + d0);
                *(bf16x8*)&Ks[key * 136 + d0] = k8;
                bf16x8 v8 = *(const bf16x8*)(vbase + (size_t)key * QKVC + d0);
                const __hip_bfloat16* ve = (const __hip_bfloat16*)&v8;
                for (int jj = 0; jj < 8; ++jj)
                    VT[(d0 + jj) * 72 + key] = ve[jj];
            }
        }
        __syncthreads();

        // S = Q K^T * scale  (16 q-rows x 64 keys per wave)
        float sv[4][4];
        for (int nt = 0; nt < 4; ++nt) {
            f32x4 s = {0.f, 0.f, 0.f, 0.f};
            for (int ks = 0; ks < 4; ++ks) {
                bf16x8 kf = *(const bf16x8*)&Ks[(nt * 16 + m16) * 136 + ks * 32 + q8 * 8];
                s = MFMA16(qf[ks], kf, s);
            }
            for (int r = 0; r < 4; ++r) sv[nt][r] = s[r] * SCALE_C;
        }
        if (kb == i) {  // causal mask on self block
            for (int nt = 0; nt < 4; ++nt) {
                const int key = nt * 16 + m16;
                for (int r = 0; r < 4; ++r) {
                    const int qr = w * 16 + q8 * 4 + r;
                    if (key > qr) sv[nt][r] = -1e9f;
                }
            }
        }

        // online softmax update (per row r; stats across 16 col-lanes)
        float alpha[4];
        for (int r = 0; r < 4; ++r) {
            float mx = fmaxf(fmaxf(sv[0][r], sv[1][r]), fmaxf(sv[2][r], sv[3][r]));
            for (int off = 1; off < 16; off <<= 1) mx = fmaxf(mx, __shfl_xor(mx, off, 64));
            const float newm = fmaxf(mrow[r], mx);
            alpha[r] = __expf(mrow[r] - newm);
            mrow[r] = newm;
            float rs = 0.f;
            for (int nt = 0; nt < 4; ++nt) {
                const float p = __expf(sv[nt][r] - newm);
                sv[nt][r] = p;
                rs += p;
            }
            for (int off = 1; off < 16; off <<= 1) rs += __shfl_xor(rs, off, 64);
            lrow[r] = lrow[r] * alpha[r] + rs;
        }

        // P: C-layout -> LDS; BARRIER (orders the cross-lane LDS round-trip,
        // prevents per-thread alias analysis from hoisting the reads) -> A-layout
        __hip_bfloat16* Pw = &Pb[w][0];
        for (int nt = 0; nt < 4; ++nt)
            for (int r = 0; r < 4; ++r)
                Pw[(q8 * 4 + r) * 72 + nt * 16 + m16] = __float2bfloat16(sv[nt][r]);

        for (int dt = 0; dt < 8; ++dt)
            for (int r = 0; r < 4; ++r)
                o[dt][r] *= alpha[r];

        __syncthreads();

        // O += P V  (k-dim = 64 keys, 2 k-steps; 8 d-tiles)
        for (int kk = 0; kk < 2; ++kk) {
            bf16x8 pf = *(const bf16x8*)&Pw[m16 * 72 + kk * 32 + q8 * 8];
            for (int dt = 0; dt < 8; ++dt) {
                bf16x8 vf = *(const bf16x8*)&VT[(dt * 16 + m16) * 72 + kk * 32 + q8 * 8];
                o[dt] = MFMA16(pf, vf, o[dt]);
            }
        }
    }

    // epilogue: O / l -> attn buffer [B*T][H*D]
    __hip_bfloat16* op = outb + (size_t)(b * Tlen + i * BLKQ) * (Hq * Dh) + h * Dh;
    for (int dt = 0; dt < 8; ++dt)
        for (int r = 0; r < 4; ++r) {
            const float val = o[dt][r] / lrow[r];
            op[(size_t)(w * 16 + q8 * 4 + r) * (Hq * Dh) + dt * 16 + m16] =
                __float2bfloat16(val);
        }
}

extern "C" void kernel_launch(void* const* d_in, const int* in_sizes, int n_in,
                              void* d_out, int out_size, void* d_ws, size_t ws_size,
                              hipStream_t stream) {
    const void* hs   = d_in[0];
    const void* cosb = d_in[1];
    const void* sinb = d_in[2];
    const void* Wq   = d_in[3];
    const void* Wk   = d_in[4];
    const void* Wv   = d_in[5];
    const void* Wo   = d_in[6];

    const int M = Bsz * Tlen;                       // 8192
    __hip_bfloat16* qkv  = (__hip_bfloat16*)d_ws;   // [8192][3072]
    __hip_bfloat16* attn = qkv + (size_t)M * QKVC;  // [8192][2048]
    int* flag = (int*)((char*)d_ws +
                       (size_t)M * QKVC * 2 + (size_t)M * HID * 2);

    // 0) runtime dtype probe (f32 vs bf16 harness presentation)
    detect_dtype<<<1, 64, 0, stream>>>(cosb, flag);
    // 1) fused QKV projection (A,B dtype-flagged; C = bf16 qkv)
    gemm_bt<true, true, false><<<dim3(QKVC / 128, M / 128), 256, 0, stream>>>(
        hs, Wq, Wk, Wv, HID, HID + 512, qkv, M, QKVC, HID, flag);
    // 2) RoPE on q,k rot dims
    rope_kernel<<<dim3(M), (Hq + HKV) * 32, 0, stream>>>(qkv, cosb, sinb, flag);
    // 3) block-sparse attention (all bf16 internal)
    attn_kernel<<<dim3(NBLK, Hq, Bsz), 256, 0, stream>>>(qkv, attn);
    // 4) output projection (B=Wo dtype-flagged; C = d_out dtype-flagged)
    gemm_bt<false, true, true><<<dim3(HID / 128, M / 128), 256, 0, stream>>>(
        attn, Wo, Wo, Wo, HID, HID, d_out, M, HID, HID, flag);
}

// Round 5
// 493.399 us; speedup vs baseline: 1.6071x; 1.6071x over previous
//
#include <hip/hip_runtime.h>
#include <hip/hip_bf16.h>

// Problem constants (HumanVAttention: B=2,T=4096,HID=2048,H=16,HKV=4,D=128,
// ROT=64, BLK=64, LOCAL=8, GLOB=1).
// DTYPE (established empirically over rounds 1-4): the harness presents ALL
// tensors in the REFERENCE dtype = float32. Round 2 passed only because its
// runtime dtype-flag selected f32 paths; hard-coded-bf16 rounds 1/3/4 NaN'd
// (f32 mantissa bits read as bf16 can encode NaN). Threshold is bf16-grade
// (8x bf16 eps), so internal compute is bf16 MFMA; I/O is f32.
#define Hq   16
#define HKV  4
#define Dh   128
#define ROT  64
#define BLKQ 64
#define NBLK 64      // T/BLK
#define Tlen 4096
#define Bsz  2
#define HID  2048
#define QKVC 3072    // 2048 q + 512 k + 512 v
#define SCALE_C 0.08838834764831845f

typedef __attribute__((ext_vector_type(8))) short bf16x8;
typedef __attribute__((ext_vector_type(4))) float f32x4;

#define MFMA16(a, b, c) __builtin_amdgcn_mfma_f32_16x16x32_bf16((a), (b), (c), 0, 0, 0)

__device__ __forceinline__ void async_copy16(__hip_bfloat16* lds, const __hip_bfloat16* g) {
    __builtin_amdgcn_global_load_lds(
        (const __attribute__((address_space(1))) void*)g,
        (__attribute__((address_space(3))) void*)lds,
        16, 0, 0);
}

// f32 -> bf16 bulk convert. blockIdx.y selects tensor {hs, Wq, Wk, Wv, Wo};
// dst regions are consecutive in ws. 8 elems/lane: 2x float4 load, 1x 16B store.
__global__ __launch_bounds__(256) void cvt_kernel(
    const float* __restrict__ s0, const float* __restrict__ s1,
    const float* __restrict__ s2, const float* __restrict__ s3,
    const float* __restrict__ s4,
    __hip_bfloat16* __restrict__ base,
    int n0, int n1, int n2, int n3, int n4)
{
    const float* src;
    size_t off, n;
    switch (blockIdx.y) {
        case 0:  src = s0; off = 0;                          n = n0; break;
        case 1:  src = s1; off = (size_t)n0;                 n = n1; break;
        case 2:  src = s2; off = (size_t)n0 + n1;            n = n2; break;
        case 3:  src = s3; off = (size_t)n0 + n1 + n2;       n = n3; break;
        default: src = s4; off = (size_t)n0 + n1 + n2 + n3;  n = n4; break;
    }
    __hip_bfloat16* dst = base + off;
    const size_t stride = (size_t)gridDim.x * 2048;
    for (size_t i = ((size_t)blockIdx.x * 256 + threadIdx.x) * 8; i < n; i += stride) {
        const float4 a = *(const float4*)(src + i);
        const float4 b = *(const float4*)(src + i + 4);
        union { bf16x8 v; __hip_bfloat16 e[8]; } u;
        u.e[0] = __float2bfloat16(a.x); u.e[1] = __float2bfloat16(a.y);
        u.e[2] = __float2bfloat16(a.z); u.e[3] = __float2bfloat16(a.w);
        u.e[4] = __float2bfloat16(b.x); u.e[5] = __float2bfloat16(b.y);
        u.e[6] = __float2bfloat16(b.z); u.e[7] = __float2bfloat16(b.w);
        *(bf16x8*)(dst + i) = u.v;
    }
}

// C[M,N] = A[M,K] * B[N,K]^T, A/B bf16 row-major (pre-converted). B split into
// up to 3 row-blocks (Wq|Wk|Wv) at col boundaries n1c, n2c (128-aligned).
// m97 structure: 128x128 tile, BK=64, global_load_lds width 16, XOR chunk
// swizzle => conflict-free ds_read_b128.
// ROPE: fuse RoPE into epilogue (q/k head tiles n0<n2c; rot half = wn==0;
// pair (d,d+32) = acc regs j and j+2); cos/sin read as f32.
// F32OUT: store C as f32 (d_out) instead of bf16.
template <bool ROPE, bool F32OUT>
__global__ __launch_bounds__(256) void gemm_bt(
    const __hip_bfloat16* __restrict__ A,
    const __hip_bfloat16* __restrict__ B0,
    const __hip_bfloat16* __restrict__ B1,
    const __hip_bfloat16* __restrict__ B2,
    int n1c, int n2c,
    void* __restrict__ C,
    int M, int N, int K,
    const float* __restrict__ cosb,
    const float* __restrict__ sinb)
{
    __shared__ __align__(16) __hip_bfloat16 As[128 * 64];
    __shared__ __align__(16) __hip_bfloat16 Bs[128 * 64];

    const int m0 = blockIdx.y * 128;
    const int n0 = blockIdx.x * 128;
    const __hip_bfloat16* Bp;
    int nb;
    if (n0 < n1c)      { Bp = B0; nb = n0; }
    else if (n0 < n2c) { Bp = B1; nb = n0 - n1c; }
    else               { Bp = B2; nb = n0 - n2c; }

    const int tid  = threadIdx.x;
    const int lane = tid & 63;
    const int w    = tid >> 6;          // wave 0..3
    const int wm   = (w >> 1) * 64;
    const int wn   = (w & 1) * 64;
    const int lr   = lane >> 3;         // row within 8-row staging group
    const int lc   = lane & 7;          // chunk 0..7
    const int m16  = lane & 15;
    const int q8   = lane >> 4;

    f32x4 acc[4][4] = {};

    for (int k0 = 0; k0 < K; k0 += 64) {
        __syncthreads();   // previous iteration's LDS reads done
        // Swizzle: LDS slot (row, cs) holds global chunk cg = cs ^ (row&7).
        for (int ii = 0; ii < 4; ++ii) {
            const int r8 = w * 32 + ii * 8;
            const int r  = r8 + lr;
            const int cg = lc ^ (r & 7);
            async_copy16(&As[r8 * 64], A  + (size_t)(m0 + r) * K + k0 + cg * 8);
            async_copy16(&Bs[r8 * 64], Bp + (size_t)(nb + r) * K + k0 + cg * 8);
        }
        __syncthreads();   // drains vmcnt before use

        for (int ks = 0; ks < 2; ++ks) {
            bf16x8 af[4], bfr[4];
            for (int t = 0; t < 4; ++t) {
                const int row = wm + t * 16 + m16;
                const int csA = (ks * 4 + q8) ^ (row & 7);
                af[t] = *(const bf16x8*)&As[row * 64 + csA * 8];
                const int col = wn + t * 16 + m16;
                const int csB = (ks * 4 + q8) ^ (col & 7);
                bfr[t] = *(const bf16x8*)&Bs[col * 64 + csB * 8];
            }
            for (int i = 0; i < 4; ++i)
                for (int j = 0; j < 4; ++j)
                    acc[i][j] = MFMA16(af[i], bfr[j], acc[i][j]);
        }
    }

    // Fused RoPE: q/k head tiles (n0 < n2c == 2560), rot half (wn == 0).
    // cols = j*16 + m16; pair (d, d+32) = regs (j, j+2), j in {0,1};
    // cos[d]==cos[d+32] (emb = concat(freqs,freqs)). cos/sin are f32.
    if (ROPE && n0 < n2c && wn == 0) {
        for (int i = 0; i < 4; ++i)
            for (int r = 0; r < 4; ++r) {
                const int bt = m0 + wm + i * 16 + q8 * 4 + r;   // b*T + t
                for (int j = 0; j < 2; ++j) {
                    const int d = j * 16 + m16;
                    const float c = cosb[(size_t)bt * ROT + d];
                    const float s = sinb[(size_t)bt * ROT + d];
                    const float x1 = acc[i][j][r];
                    const float x2 = acc[i][j + 2][r];
                    acc[i][j][r]     = x1 * c - x2 * s;
                    acc[i][j + 2][r] = x2 * c + x1 * s;
                }
            }
    }

    // epilogue: C layout col=lane&15, row=(lane>>4)*4+reg
    for (int i = 0; i < 4; ++i)
        for (int j = 0; j < 4; ++j)
            for (int r = 0; r < 4; ++r) {
                const int row = m0 + wm + i * 16 + q8 * 4 + r;
                const int col = n0 + wn + j * 16 + m16;
                if (F32OUT)
                    ((float*)C)[(size_t)row * N + col] = acc[i][j][r];
                else
                    ((__hip_bfloat16*)C)[(size_t)row * N + col] =
                        __float2bfloat16(acc[i][j][r]);
            }
}

// Block-sparse flash attention. Grid (qblock=64, head=16, batch=2), 256 threads.
// Wave w owns q rows w*16..w*16+15. Per KV block: stage K (row-major vector
// writes) and V^T (scalar transpose, key=lane => 32 banks 2-way = free) in LDS;
// QK^T MFMA; in-register online softmax; P via per-wave LDS with __syncthreads
// between write and read (C->A layout); PV MFMA. All bf16 internal.
__global__ __launch_bounds__(256) void attn_kernel(
    const __hip_bfloat16* __restrict__ qkv,
    __hip_bfloat16* __restrict__ outb)
{
    const int i   = blockIdx.x;   // q block
    const int h   = blockIdx.y;
    const int b   = blockIdx.z;
    const int kvh = h >> 2;
    const int tid  = threadIdx.x;
    const int lane = tid & 63;
    const int w    = tid >> 6;
    const int m16  = lane & 15;
    const int q8   = lane >> 4;

    __shared__ __align__(16) __hip_bfloat16 Ks[64 * 136];   // K rows padded +8
    __shared__ __align__(16) __hip_bfloat16 VT[128 * 72];   // V^T rows padded +8
    __shared__ __align__(16) __hip_bfloat16 Pb[4][16 * 72]; // per-wave P scratch

    // Q fragments (A-layout): row = lane&15 (+w*16), k-chunk = (lane>>4)*8
    bf16x8 qf[4];
    {
        const __hip_bfloat16* qp =
            qkv + (size_t)(b * Tlen + i * BLKQ + w * 16 + m16) * QKVC + h * Dh + q8 * 8;
        for (int ks = 0; ks < 4; ++ks) qf[ks] = *(const bf16x8*)(qp + ks * 32);
    }

    f32x4 o[8] = {};
    float mrow[4] = {-1e30f, -1e30f, -1e30f, -1e30f};
    float lrow[4] = {0.f, 0.f, 0.f, 0.f};

    const int nsel = (i + 1 < 9) ? (i + 1) : 9;
    for (int j = 0; j < nsel; ++j) {
        const int kb = (i <= 7) ? j : ((j == 0) ? 0 : (i - 8 + j));

        __syncthreads();  // LDS reuse guard (prev iter's reads done)
        {
            const __hip_bfloat16* kbase =
                qkv + (size_t)(b * Tlen + kb * BLKQ) * QKVC + HID + kvh * Dh;
            const __hip_bfloat16* vbase = kbase + 512;
            // K: row-major vector copy (b128 writes, conflict-free)
            for (int c = tid; c < 1024; c += 256) {
                const int key = c >> 4;
                const int d0  = (c & 15) * 8;
                *(bf16x8*)&Ks[key * 136 + d0] =
                    *(const bf16x8*)(kbase + (size_t)key * QKVC + d0);
            }
            // V^T: scalar transpose; key = lane => 64 lanes span all 32 banks
            // 2-way (free per m136).
            for (int c = tid; c < 1024; c += 256) {
                const int key = c & 63;
                const int d0  = (c >> 6) * 8;
                bf16x8 v8 = *(const bf16x8*)(vbase + (size_t)key * QKVC + d0);
                const __hip_bfloat16* ve = (const __hip_bfloat16*)&v8;
                for (int jj = 0; jj < 8; ++jj)
                    VT[(d0 + jj) * 72 + key] = ve[jj];
            }
        }
        __syncthreads();

        // S = Q K^T * scale  (16 q-rows x 64 keys per wave)
        float sv[4][4];
        for (int nt = 0; nt < 4; ++nt) {
            f32x4 s = {0.f, 0.f, 0.f, 0.f};
            for (int ks = 0; ks < 4; ++ks) {
                bf16x8 kf = *(const bf16x8*)&Ks[(nt * 16 + m16) * 136 + ks * 32 + q8 * 8];
                s = MFMA16(qf[ks], kf, s);
            }
            for (int r = 0; r < 4; ++r) sv[nt][r] = s[r] * SCALE_C;
        }
        if (kb == i) {  // causal mask on self block
            for (int nt = 0; nt < 4; ++nt) {
                const int key = nt * 16 + m16;
                for (int r = 0; r < 4; ++r) {
                    const int qr = w * 16 + q8 * 4 + r;
                    if (key > qr) sv[nt][r] = -1e9f;
                }
            }
        }

        // online softmax update (per row r; stats across 16 col-lanes)
        float alpha[4];
        for (int r = 0; r < 4; ++r) {
            float mx = fmaxf(fmaxf(sv[0][r], sv[1][r]), fmaxf(sv[2][r], sv[3][r]));
            for (int off = 1; off < 16; off <<= 1) mx = fmaxf(mx, __shfl_xor(mx, off, 64));
            const float newm = fmaxf(mrow[r], mx);
            alpha[r] = __expf(mrow[r] - newm);
            mrow[r] = newm;
            float rs = 0.f;
            for (int nt = 0; nt < 4; ++nt) {
                const float p = __expf(sv[nt][r] - newm);
                sv[nt][r] = p;
                rs += p;
            }
            for (int off = 1; off < 16; off <<= 1) rs += __shfl_xor(rs, off, 64);
            lrow[r] = lrow[r] * alpha[r] + rs;
        }

        // P: C-layout -> per-wave LDS -> A-layout (barrier-ordered)
        __hip_bfloat16* Pw = &Pb[w][0];
        for (int nt = 0; nt < 4; ++nt)
            for (int r = 0; r < 4; ++r)
                Pw[(q8 * 4 + r) * 72 + nt * 16 + m16] = __float2bfloat16(sv[nt][r]);

        for (int dt = 0; dt < 8; ++dt)
            for (int r = 0; r < 4; ++r)
                o[dt][r] *= alpha[r];

        __syncthreads();

        // O += P V  (k-dim = 64 keys, 2 k-steps; 8 d-tiles)
        for (int kk = 0; kk < 2; ++kk) {
            bf16x8 pf = *(const bf16x8*)&Pw[m16 * 72 + kk * 32 + q8 * 8];
            for (int dt = 0; dt < 8; ++dt) {
                bf16x8 vf = *(const bf16x8*)&VT[(dt * 16 + m16) * 72 + kk * 32 + q8 * 8];
                o[dt] = MFMA16(pf, vf, o[dt]);
            }
        }
    }

    // epilogue: O * (1/l) -> attn buffer [B*T][H*D] (bf16)
    float rcp[4];
    for (int r = 0; r < 4; ++r) rcp[r] = 1.0f / lrow[r];
    __hip_bfloat16* op = outb + (size_t)(b * Tlen + i * BLKQ) * (Hq * Dh) + h * Dh;
    for (int dt = 0; dt < 8; ++dt)
        for (int r = 0; r < 4; ++r) {
            const float val = o[dt][r] * rcp[r];
            op[(size_t)(w * 16 + q8 * 4 + r) * (Hq * Dh) + dt * 16 + m16] =
                __float2bfloat16(val);
        }
}

extern "C" void kernel_launch(void* const* d_in, const int* in_sizes, int n_in,
                              void* d_out, int out_size, void* d_ws, size_t ws_size,
                              hipStream_t stream) {
    const float* hs   = (const float*)d_in[0];
    const float* cosb = (const float*)d_in[1];
    const float* sinb = (const float*)d_in[2];
    const float* Wq   = (const float*)d_in[3];
    const float* Wk   = (const float*)d_in[4];
    const float* Wv   = (const float*)d_in[5];
    const float* Wo   = (const float*)d_in[6];

    const int M = Bsz * Tlen;                 // 8192
    const int nHS = M * HID;                  // 16,777,216
    const int nWq = Hq * Dh * HID;            //  4,194,304
    const int nWk = HKV * Dh * HID;           //  1,048,576
    const int nWv = nWk;
    const int nWo = HID * Hq * Dh;            //  4,194,304

    // ws layout (bf16 elements, consecutive): hs | Wq | Wk | Wv | Wo | qkv | attn
    __hip_bfloat16* hsb  = (__hip_bfloat16*)d_ws;
    __hip_bfloat16* wqb  = hsb + nHS;
    __hip_bfloat16* wkb  = wqb + nWq;
    __hip_bfloat16* wvb  = wkb + nWk;
    __hip_bfloat16* wob  = wvb + nWv;
    __hip_bfloat16* qkv  = wob + nWo;               // [8192][3072]
    __hip_bfloat16* attn = qkv + (size_t)M * QKVC;  // [8192][2048]

    // 0) f32 -> bf16 conversion of hs + all weights
    cvt_kernel<<<dim3(8192, 5), 256, 0, stream>>>(
        hs, Wq, Wk, Wv, Wo, hsb, nHS, nWq, nWk, nWv, nWo);
    // 1) fused QKV projection + RoPE epilogue (bf16 out)
    gemm_bt<true, false><<<dim3(QKVC / 128, M / 128), 256, 0, stream>>>(
        hsb, wqb, wkb, wvb, HID, HID + 512, qkv, M, QKVC, HID, cosb, sinb);
    // 2) block-sparse attention (bf16)
    attn_kernel<<<dim3(NBLK, Hq, Bsz), 256, 0, stream>>>(qkv, attn);
    // 3) output projection (f32 out to d_out)
    gemm_bt<false, true><<<dim3(HID / 128, M / 128), 256, 0, stream>>>(
        attn, wob, wob, wob, HID, HID, d_out, M, HID, HID, nullptr, nullptr);
}